// Round 3
// baseline (130.199 us; speedup 1.0000x reference)
//
#include <hip/hip_runtime.h>
#include <math.h>

#define NLIB 128
#define INFBITS 0x7F800000u

typedef float f32x4 __attribute__((ext_vector_type(4)));

static __device__ __forceinline__ int iclamp(int v, int lo, int hi) {
    return v < lo ? lo : (v > hi ? hi : v);
}

// ---------------------------------------------------------------------------
// Kernel 1: fused image-level kNN (row distances + rank select + z_score)
// plus init of the three smin-bits buffers. 1 block x 1024 threads.
// ---------------------------------------------------------------------------
__global__ __launch_bounds__(1024)
void knn_kernel(const float* __restrict__ z, const float* __restrict__ z_lib,
                const int* __restrict__ kp, float* __restrict__ zscore,
                int* __restrict__ idx, unsigned* __restrict__ sb0,
                unsigned* __restrict__ sb1, unsigned* __restrict__ sb2) {
    __shared__ float dist2[NLIB];
    __shared__ float contrib[NLIB];
    const int tid = threadIdx.x, wave = tid >> 6, lane = tid & 63;
    for (int i = tid; i < 3136; i += 1024) sb0[i] = INFBITS;
    for (int i = tid; i < 784;  i += 1024) sb1[i] = INFBITS;
    for (int i = tid; i < 196;  i += 1024) sb2[i] = INFBITS;
    const f32x4* __restrict__ zq = (const f32x4*)z;
    for (int r = 0; r < 8; ++r) {                       // 16 waves * 8 = 128 rows
        const int n = wave * 8 + r;
        const f32x4* __restrict__ row = (const f32x4*)(z_lib + (size_t)n * 1024);
        f32x4 s = {};
#pragma unroll
        for (int i = 0; i < 4; ++i) {
            f32x4 a = row[lane + i * 64];
            f32x4 b = zq[lane + i * 64];
            f32x4 d = a - b;
            s += d * d;
        }
        float acc = s[0] + s[1] + s[2] + s[3];
        for (int off = 32; off > 0; off >>= 1) acc += __shfl_down(acc, off, 64);
        if (lane == 0) dist2[n] = acc;
    }
    __syncthreads();
    const int k = *kp;
    if (tid < NLIB) {
        const float dd = dist2[tid];
        int rank = 0;
#pragma unroll 8
        for (int m = 0; m < NLIB; ++m) {
            const float dm = dist2[m];
            rank += (dm < dd || (dm == dd && m < tid)) ? 1 : 0;
        }
        if (rank < k) idx[rank] = tid;
        contrib[tid] = (rank < k) ? sqrtf(dd) : 0.f;
    }
    __syncthreads();
    if (tid == 0) {
        float s = 0.f;
        for (int m = 0; m < NLIB; ++m) s += contrib[m];   // fixed order
        zscore[0] = s / (float)k;
    }
}

// ---------------------------------------------------------------------------
// Kernel 2: per-level partial squared distances, 8 n-streams per thread.
// fmap quad loaded ONCE per 8 lib quads (8x fewer fmap re-reads); lib loads
// nontemporal (streamed once, keep L2 for fmap). Out-of-range n clamped to
// k-1 -> duplicate same-address loads (L1 hits), stores guarded.
// ---------------------------------------------------------------------------
template <int C, int NQ, int CCH>
static __device__ __forceinline__ void dist_level(const float* __restrict__ lib,
                                                  const float* __restrict__ fmap,
                                                  const int* __restrict__ idx,
                                                  int k, int nc, int w,
                                                  f32x4* __restrict__ d2) {
    constexpr int CL = C / CCH;
    if (w >= CCH * NQ) return;
    const int cc = w / NQ;
    const int q  = w - cc * NQ;
    const f32x4* __restrict__ fp = (const f32x4*)fmap + (size_t)(cc * CL) * NQ + q;
    const f32x4* lp[8];
#pragma unroll
    for (int j = 0; j < 8; ++j) {
        int n = nc + j;
        n = n < k ? n : k - 1;
        lp[j] = (const f32x4*)lib + ((size_t)idx[n] * C + cc * CL) * NQ + q;
    }
    f32x4 acc[8] = {};
#pragma unroll 2
    for (int c = 0; c < CL; ++c) {
        const f32x4 f = fp[(size_t)c * NQ];
#pragma unroll
        for (int j = 0; j < 8; ++j) {
            f32x4 a = __builtin_nontemporal_load(lp[j] + (size_t)c * NQ);
            f32x4 d = a - f;
            acc[j] += d * d;
        }
    }
#pragma unroll
    for (int j = 0; j < 8; ++j)
        if (nc + j < k) d2[((size_t)cc * NLIB + nc + j) * NQ + q] = acc[j];
}

__global__ __launch_bounds__(256)
void dist_all_kernel(const float* __restrict__ lib0, const float* __restrict__ fmap0,
                     const float* __restrict__ lib1, const float* __restrict__ fmap1,
                     const float* __restrict__ lib2, const float* __restrict__ fmap2,
                     const int* __restrict__ kp, const int* __restrict__ idx,
                     f32x4* __restrict__ d2_0, f32x4* __restrict__ d2_1,
                     f32x4* __restrict__ d2_2) {
    const int k = *kp;
    const int nc = blockIdx.y * 8;
    if (nc >= k) return;
    const int bx = blockIdx.x;
    if (bx < 49) {                // L0: 16cc x 784q = 12544 = 49*256
        dist_level<256, 784, 16>(lib0, fmap0, idx, k, nc, bx * 256 + threadIdx.x, d2_0);
    } else if (bx < 74) {         // L1: 32cc x 196q = 6272 -> 25 blocks
        dist_level<512, 196, 32>(lib1, fmap1, idx, k, nc, (bx - 49) * 256 + threadIdx.x, d2_1);
    } else {                      // L2: 64cc x 49q = 3136 -> 13 blocks
        dist_level<1024, 49, 64>(lib2, fmap2, idx, k, nc, (bx - 74) * 256 + threadIdx.x, d2_2);
    }
}

// ---------------------------------------------------------------------------
// Kernel 3: min over k via atomicMin on uint bits (d2 >= 0 -> monotone).
// grid = (5 pixel-blocks, 32 n-chunks of 4).
// ---------------------------------------------------------------------------
template <int NQ, int CCH>
static __device__ __forceinline__ void min_level(const f32x4* __restrict__ d2, int q,
                                                 int n0, int n1, unsigned* __restrict__ sb) {
    float mnx = 3.4e38f, mny = 3.4e38f, mnz = 3.4e38f, mnw = 3.4e38f;
    for (int n = n0; n < n1; ++n) {
        f32x4 s = {};
#pragma unroll
        for (int cc = 0; cc < CCH; ++cc) s += d2[((size_t)cc * NLIB + n) * NQ + q];
        mnx = fminf(mnx, s[0]); mny = fminf(mny, s[1]);
        mnz = fminf(mnz, s[2]); mnw = fminf(mnw, s[3]);
    }
    atomicMin(sb + q * 4 + 0, __float_as_uint(mnx));
    atomicMin(sb + q * 4 + 1, __float_as_uint(mny));
    atomicMin(sb + q * 4 + 2, __float_as_uint(mnz));
    atomicMin(sb + q * 4 + 3, __float_as_uint(mnw));
}

__global__ __launch_bounds__(256)
void min_all_kernel(const f32x4* __restrict__ d2_0, const f32x4* __restrict__ d2_1,
                    const f32x4* __restrict__ d2_2, const int* __restrict__ kp,
                    unsigned* __restrict__ sb0, unsigned* __restrict__ sb1,
                    unsigned* __restrict__ sb2) {
    const int k = *kp;
    const int n0 = blockIdx.y * 4;
    if (n0 >= k) return;
    const int n1 = min(n0 + 4, k);
    const int t = blockIdx.x * 256 + threadIdx.x;
    if (t < 784)       min_level<784, 16>(d2_0, t, n0, n1, sb0);
    else if (t < 980)  min_level<196, 32>(d2_1, t - 784, n0, n1, sb1);
    else if (t < 1029) min_level<49, 64>(d2_2, t - 980, n0, n1, sb2);
}

// ---------------------------------------------------------------------------
// Kernel 4: bilinear upsample (half-pixel, edge clamp) of sqrt(smin-bits),
// summed across levels, fused with horizontal 17-tap blur (reflect).
// ---------------------------------------------------------------------------
static __device__ __forceinline__ void samp(int o, float inv_f, int sz, int& i0, int& i1,
                                            float& fr) {
    float c  = (o + 0.5f) * inv_f - 0.5f;   // inv_f power of two: exact
    float fl = floorf(c);
    fr = c - fl;
    int i = (int)fl;
    i0 = iclamp(i, 0, sz - 1);
    i1 = iclamp(i + 1, 0, sz - 1);
}

static __device__ __forceinline__ float ldsq(const unsigned* __restrict__ sb, int w, int y, int x) {
    return sqrtf(__uint_as_float(sb[y * w + x]));
}

static __device__ __forceinline__ float bilerp_sq(const unsigned* __restrict__ sb, int w,
                                                  int y0, int y1, int x0, int x1,
                                                  float fy, float fx) {
    float a = ldsq(sb, w, y0, x0), b = ldsq(sb, w, y0, x1);
    float c = ldsq(sb, w, y1, x0), d = ldsq(sb, w, y1, x1);
    float top = a + (b - a) * fx;
    float bot = c + (d - c) * fx;
    return top + (bot - top) * fy;
}

static __device__ __forceinline__ int reflect224(int i) {
    if (i < 0) i = -i;
    if (i > 223) i = 446 - i;
    return i;
}

static __device__ __forceinline__ void gauss_w(float* w) {
    float tot = 0.f;
#pragma unroll
    for (int j = 0; j < 17; ++j) {
        float t = (j - 8) * 0.25f;
        w[j] = expf(-0.5f * t * t);
        tot += w[j];
    }
    float inv = 1.f / tot;
#pragma unroll
    for (int j = 0; j < 17; ++j) w[j] *= inv;
}

__global__ __launch_bounds__(256)
void up_blurh_kernel(const unsigned* __restrict__ sb0, const unsigned* __restrict__ sb1,
                     const unsigned* __restrict__ sb2, float* __restrict__ tmp) {
    __shared__ float row[224];
    const int y = blockIdx.x, x = threadIdx.x;
    int y0, y1, x0, x1; float fy, fx;
    if (x < 224) {
        float v = 0.f;
        samp(y, 0.25f, 56, y0, y1, fy);   samp(x, 0.25f, 56, x0, x1, fx);
        v += bilerp_sq(sb0, 56, y0, y1, x0, x1, fy, fx);
        samp(y, 0.125f, 28, y0, y1, fy);  samp(x, 0.125f, 28, x0, x1, fx);
        v += bilerp_sq(sb1, 28, y0, y1, x0, x1, fy, fx);
        samp(y, 0.0625f, 14, y0, y1, fy); samp(x, 0.0625f, 14, x0, x1, fx);
        v += bilerp_sq(sb2, 14, y0, y1, x0, x1, fy, fx);
        row[x] = v;
    }
    __syncthreads();
    if (x < 224) {
        float w[17];
        gauss_w(w);
        float acc = 0.f;
#pragma unroll
        for (int j = 0; j < 17; ++j) acc += w[j] * row[reflect224(x + j - 8)];
        tmp[y * 224 + x] = acc;
    }
}

__global__ __launch_bounds__(256)
void blur_v_kernel(const float* __restrict__ in, float* __restrict__ out) {
    const int i = blockIdx.x * blockDim.x + threadIdx.x;
    if (i >= 224 * 224) return;
    const int y = i / 224, x = i % 224;
    float w[17];
    gauss_w(w);
    float acc = 0.f;
#pragma unroll
    for (int j = 0; j < 17; ++j) acc += w[j] * in[reflect224(y + j - 8) * 224 + x];
    out[i] = acc;
}

// ---------------------------------------------------------------------------
// Launch
// ---------------------------------------------------------------------------
extern "C" void kernel_launch(void* const* d_in, const int* in_sizes, int n_in,
                              void* d_out, int out_size, void* d_ws, size_t ws_size,
                              hipStream_t stream) {
    const float* z     = (const float*)d_in[0];
    const float* z_lib = (const float*)d_in[1];
    const float* fmap0 = (const float*)d_in[2];
    const float* fmap1 = (const float*)d_in[3];
    const float* fmap2 = (const float*)d_in[4];
    const float* lib0  = (const float*)d_in[5];
    const float* lib1  = (const float*)d_in[6];
    const float* lib2  = (const float*)d_in[7];
    const int*   kp    = (const int*)d_in[8];
    float* out = (float*)d_out;

    // workspace layout (16B aligned)
    constexpr size_t OFF_IDX  = 0;                       // 128 i32
    constexpr size_t OFF_SB0  = 1024;                    // 3136 u32
    constexpr size_t OFF_SB1  = 16384;                   // 784 u32
    constexpr size_t OFF_SB2  = 20480;                   // 196 u32
    constexpr size_t OFF_TMP  = 24576;                   // 50176 f32
    constexpr size_t OFF_D2_0 = 262144;
    constexpr size_t SZ_D2_0  = (size_t)16 * NLIB * 784 * 16;
    constexpr size_t OFF_D2_1 = OFF_D2_0 + SZ_D2_0;
    constexpr size_t SZ_D2_1  = (size_t)32 * NLIB * 196 * 16;
    constexpr size_t OFF_D2_2 = OFF_D2_1 + SZ_D2_1;

    char* ws = (char*)d_ws;
    int*      idx  = (int*)(ws + OFF_IDX);
    unsigned* sb0  = (unsigned*)(ws + OFF_SB0);
    unsigned* sb1  = (unsigned*)(ws + OFF_SB1);
    unsigned* sb2  = (unsigned*)(ws + OFF_SB2);
    float*    tmp  = (float*)(ws + OFF_TMP);
    f32x4*    d2_0 = (f32x4*)(ws + OFF_D2_0);
    f32x4*    d2_1 = (f32x4*)(ws + OFF_D2_1);
    f32x4*    d2_2 = (f32x4*)(ws + OFF_D2_2);

    // 1) kNN: row distances + select + z_score + smin init
    knn_kernel<<<dim3(1), dim3(1024), 0, stream>>>(z, z_lib, kp, out, idx, sb0, sb1, sb2);
    // 2) per-level distances, 8 n-streams per thread
    dist_all_kernel<<<dim3(87, 16), dim3(256), 0, stream>>>(
        lib0, fmap0, lib1, fmap1, lib2, fmap2, kp, idx, d2_0, d2_1, d2_2);
    // 3) min over k
    min_all_kernel<<<dim3(5, 32), dim3(256), 0, stream>>>(d2_0, d2_1, d2_2, kp, sb0, sb1, sb2);
    // 4) upsample + sum + blur-H
    up_blurh_kernel<<<dim3(224), dim3(256), 0, stream>>>(sb0, sb1, sb2, tmp);
    // 5) blur-V
    blur_v_kernel<<<dim3(196), dim3(256), 0, stream>>>(tmp, out + 1);
}

// Round 4
// 113.495 us; speedup vs baseline: 1.1472x; 1.1472x over previous
//
#include <hip/hip_runtime.h>
#include <math.h>

#define NLIB 128
#define INFBITS 0x7F800000u

typedef float f32x4 __attribute__((ext_vector_type(4)));

static __device__ __forceinline__ int iclamp(int v, int lo, int hi) {
    return v < lo ? lo : (v > hi ? hi : v);
}

// ---------------------------------------------------------------------------
// Kernel 1: per-row squared distance ||z_lib[n]-z||^2. 128 blocks x 256 thr.
// ---------------------------------------------------------------------------
__global__ __launch_bounds__(256)
void row_dist_kernel(const float* __restrict__ z, const float* __restrict__ z_lib,
                     float* __restrict__ dist2) {
    const int n = blockIdx.x;
    const int tid = threadIdx.x, wave = tid >> 6, lane = tid & 63;
    const f32x4 a = ((const f32x4*)(z_lib + (size_t)n * 1024))[tid];
    const f32x4 b = ((const f32x4*)z)[tid];
    f32x4 d = a - b;
    f32x4 s = d * d;
    float acc = s[0] + s[1] + s[2] + s[3];
    for (int off = 32; off > 0; off >>= 1) acc += __shfl_down(acc, off, 64);
    __shared__ float ws4[4];
    if (lane == 0) ws4[wave] = acc;
    __syncthreads();
    if (tid == 0) dist2[n] = ws4[0] + ws4[1] + ws4[2] + ws4[3];
}

// ---------------------------------------------------------------------------
// Kernel 2: rank-select k smallest -> idx[rank]=n, z_score; init smin bits.
// ---------------------------------------------------------------------------
__global__ __launch_bounds__(128)
void select_kernel(const float* __restrict__ dist2, const int* __restrict__ kp,
                   float* __restrict__ zscore, int* __restrict__ idx,
                   unsigned* __restrict__ sb0, unsigned* __restrict__ sb1,
                   unsigned* __restrict__ sb2) {
    __shared__ float d[NLIB];
    __shared__ float contrib[NLIB];
    const int tid = threadIdx.x;
    d[tid] = dist2[tid];
    for (int i = tid; i < 3136; i += 128) sb0[i] = INFBITS;
    for (int i = tid; i < 784;  i += 128) sb1[i] = INFBITS;
    for (int i = tid; i < 196;  i += 128) sb2[i] = INFBITS;
    __syncthreads();
    const int k = *kp;
    const float dd = d[tid];
    int rank = 0;
#pragma unroll 8
    for (int m = 0; m < NLIB; ++m) {
        const float dm = d[m];
        rank += (dm < dd || (dm == dd && m < tid)) ? 1 : 0;
    }
    if (rank < k) idx[rank] = tid;
    contrib[tid] = (rank < k) ? sqrtf(dd) : 0.f;
    __syncthreads();
    if (tid == 0) {
        float s = 0.f;
        for (int m = 0; m < NLIB; ++m) s += contrib[m];   // fixed order
        zscore[0] = s / (float)k;
    }
}

// ---------------------------------------------------------------------------
// Kernel 3: FUSED dist+min. Block = (pixel-tile of 64 quads, n). Wave w sums
// its C/4 channel chunk for 64 quads; 4 partials combined in LDS in fixed
// order; atomicMin(uint bits) into smin — no intermediate d2 buffer.
// ---------------------------------------------------------------------------
template <int C, int NQ>
static __device__ __forceinline__ void dist_min_level(const float* __restrict__ lib,
                                                      const float* __restrict__ fmap,
                                                      int img, int qt,
                                                      unsigned* __restrict__ sb) {
    constexpr int CW = C / 4;                       // channels per wave
    const int tid = threadIdx.x;
    const int wave = tid >> 6, lane = tid & 63;
    const int q = qt * 64 + lane;
    const bool active = q < NQ;
    const int qc = active ? q : NQ - 1;             // clamp: dup loads, L1 hits
    const f32x4* __restrict__ lp = (const f32x4*)lib + ((size_t)img * C + wave * CW) * NQ + qc;
    const f32x4* __restrict__ fp = (const f32x4*)fmap + ((size_t)wave * CW) * NQ + qc;
    f32x4 acc = {};
#pragma unroll 8
    for (int c = 0; c < CW; ++c) {
        f32x4 a = lp[(size_t)c * NQ];
        f32x4 f = fp[(size_t)c * NQ];
        f32x4 d = a - f;
        acc += d * d;
    }
    __shared__ f32x4 part[4][64];
    part[wave][lane] = acc;
    __syncthreads();
    if (wave == 0 && active) {
        f32x4 s = ((part[0][lane] + part[1][lane]) + part[2][lane]) + part[3][lane];
        atomicMin(sb + q * 4 + 0, __float_as_uint(s[0]));
        atomicMin(sb + q * 4 + 1, __float_as_uint(s[1]));
        atomicMin(sb + q * 4 + 2, __float_as_uint(s[2]));
        atomicMin(sb + q * 4 + 3, __float_as_uint(s[3]));
    }
}

__global__ __launch_bounds__(256)
void dist_min_kernel(const float* __restrict__ lib0, const float* __restrict__ fmap0,
                     const float* __restrict__ lib1, const float* __restrict__ fmap1,
                     const float* __restrict__ lib2, const float* __restrict__ fmap2,
                     const int* __restrict__ kp, const int* __restrict__ idx,
                     unsigned* __restrict__ sb0, unsigned* __restrict__ sb1,
                     unsigned* __restrict__ sb2) {
    const int t = blockIdx.x;                       // padded to 24 (XCD-stable map)
    if (t >= 18) return;
    const int n = blockIdx.y;
    if (n >= *kp) return;
    const int img = idx[n];
    if (t < 13)      dist_min_level<256, 784>(lib0, fmap0, img, t, sb0);       // 13 tiles
    else if (t < 17) dist_min_level<512, 196>(lib1, fmap1, img, t - 13, sb1);  // 4 tiles
    else             dist_min_level<1024, 49>(lib2, fmap2, img, t - 17, sb2);  // 1 tile
}

// ---------------------------------------------------------------------------
// Kernel 4: bilinear upsample (half-pixel, edge clamp) of sqrt(smin-bits),
// summed across levels, fused with horizontal 17-tap blur (reflect).
// ---------------------------------------------------------------------------
static __device__ __forceinline__ void samp(int o, float inv_f, int sz, int& i0, int& i1,
                                            float& fr) {
    float c  = (o + 0.5f) * inv_f - 0.5f;   // inv_f power of two: exact
    float fl = floorf(c);
    fr = c - fl;
    int i = (int)fl;
    i0 = iclamp(i, 0, sz - 1);
    i1 = iclamp(i + 1, 0, sz - 1);
}

static __device__ __forceinline__ float ldsq(const unsigned* __restrict__ sb, int w, int y, int x) {
    return sqrtf(__uint_as_float(sb[y * w + x]));
}

static __device__ __forceinline__ float bilerp_sq(const unsigned* __restrict__ sb, int w,
                                                  int y0, int y1, int x0, int x1,
                                                  float fy, float fx) {
    float a = ldsq(sb, w, y0, x0), b = ldsq(sb, w, y0, x1);
    float c = ldsq(sb, w, y1, x0), d = ldsq(sb, w, y1, x1);
    float top = a + (b - a) * fx;
    float bot = c + (d - c) * fx;
    return top + (bot - top) * fy;
}

static __device__ __forceinline__ int reflect224(int i) {
    if (i < 0) i = -i;
    if (i > 223) i = 446 - i;
    return i;
}

static __device__ __forceinline__ void gauss_w(float* w) {
    float tot = 0.f;
#pragma unroll
    for (int j = 0; j < 17; ++j) {
        float t = (j - 8) * 0.25f;
        w[j] = expf(-0.5f * t * t);
        tot += w[j];
    }
    float inv = 1.f / tot;
#pragma unroll
    for (int j = 0; j < 17; ++j) w[j] *= inv;
}

__global__ __launch_bounds__(256)
void up_blurh_kernel(const unsigned* __restrict__ sb0, const unsigned* __restrict__ sb1,
                     const unsigned* __restrict__ sb2, float* __restrict__ tmp) {
    __shared__ float row[224];
    const int y = blockIdx.x, x = threadIdx.x;
    int y0, y1, x0, x1; float fy, fx;
    if (x < 224) {
        float v = 0.f;
        samp(y, 0.25f, 56, y0, y1, fy);   samp(x, 0.25f, 56, x0, x1, fx);
        v += bilerp_sq(sb0, 56, y0, y1, x0, x1, fy, fx);
        samp(y, 0.125f, 28, y0, y1, fy);  samp(x, 0.125f, 28, x0, x1, fx);
        v += bilerp_sq(sb1, 28, y0, y1, x0, x1, fy, fx);
        samp(y, 0.0625f, 14, y0, y1, fy); samp(x, 0.0625f, 14, x0, x1, fx);
        v += bilerp_sq(sb2, 14, y0, y1, x0, x1, fy, fx);
        row[x] = v;
    }
    __syncthreads();
    if (x < 224) {
        float w[17];
        gauss_w(w);
        float acc = 0.f;
#pragma unroll
        for (int j = 0; j < 17; ++j) acc += w[j] * row[reflect224(x + j - 8)];
        tmp[y * 224 + x] = acc;
    }
}

__global__ __launch_bounds__(256)
void blur_v_kernel(const float* __restrict__ in, float* __restrict__ out) {
    const int i = blockIdx.x * blockDim.x + threadIdx.x;
    if (i >= 224 * 224) return;
    const int y = i / 224, x = i % 224;
    float w[17];
    gauss_w(w);
    float acc = 0.f;
#pragma unroll
    for (int j = 0; j < 17; ++j) acc += w[j] * in[reflect224(y + j - 8) * 224 + x];
    out[i] = acc;
}

// ---------------------------------------------------------------------------
// Launch
// ---------------------------------------------------------------------------
extern "C" void kernel_launch(void* const* d_in, const int* in_sizes, int n_in,
                              void* d_out, int out_size, void* d_ws, size_t ws_size,
                              hipStream_t stream) {
    const float* z     = (const float*)d_in[0];
    const float* z_lib = (const float*)d_in[1];
    const float* fmap0 = (const float*)d_in[2];
    const float* fmap1 = (const float*)d_in[3];
    const float* fmap2 = (const float*)d_in[4];
    const float* lib0  = (const float*)d_in[5];
    const float* lib1  = (const float*)d_in[6];
    const float* lib2  = (const float*)d_in[7];
    const int*   kp    = (const int*)d_in[8];
    float* out = (float*)d_out;

    // workspace layout (16B aligned)
    constexpr size_t OFF_IDX   = 0;        // 128 i32
    constexpr size_t OFF_DIST2 = 1024;     // 128 f32
    constexpr size_t OFF_SB0   = 2048;     // 3136 u32
    constexpr size_t OFF_SB1   = 16384;    // 784 u32
    constexpr size_t OFF_SB2   = 20480;    // 196 u32
    constexpr size_t OFF_TMP   = 24576;    // 50176 f32

    char* ws = (char*)d_ws;
    int*      idx   = (int*)(ws + OFF_IDX);
    float*    dist2 = (float*)(ws + OFF_DIST2);
    unsigned* sb0   = (unsigned*)(ws + OFF_SB0);
    unsigned* sb1   = (unsigned*)(ws + OFF_SB1);
    unsigned* sb2   = (unsigned*)(ws + OFF_SB2);
    float*    tmp   = (float*)(ws + OFF_TMP);

    // 1) row distances (parallel across 128 blocks)
    row_dist_kernel<<<dim3(NLIB), dim3(256), 0, stream>>>(z, z_lib, dist2);
    // 2) rank-select + z_score + smin init
    select_kernel<<<dim3(1), dim3(128), 0, stream>>>(dist2, kp, out, idx, sb0, sb1, sb2);
    // 3) fused per-level distances + min (no intermediate buffer)
    dist_min_kernel<<<dim3(24, NLIB), dim3(256), 0, stream>>>(
        lib0, fmap0, lib1, fmap1, lib2, fmap2, kp, idx, sb0, sb1, sb2);
    // 4) upsample + sum + blur-H
    up_blurh_kernel<<<dim3(224), dim3(256), 0, stream>>>(sb0, sb1, sb2, tmp);
    // 5) blur-V
    blur_v_kernel<<<dim3(196), dim3(256), 0, stream>>>(tmp, out + 1);
}

// Round 5
// 82.396 us; speedup vs baseline: 1.5802x; 1.3774x over previous
//
#include <hip/hip_runtime.h>
#include <math.h>

#define NLIB 128
#define INFBITS 0x7F800000u

typedef float f32x4 __attribute__((ext_vector_type(4)));

static __device__ __forceinline__ int iclamp(int v, int lo, int hi) {
    return v < lo ? lo : (v > hi ? hi : v);
}

// ---------------------------------------------------------------------------
// Kernel 1: per-row squared distance ||z_lib[n]-z||^2. 128 blocks x 256 thr.
// ---------------------------------------------------------------------------
__global__ __launch_bounds__(256)
void row_dist_kernel(const float* __restrict__ z, const float* __restrict__ z_lib,
                     float* __restrict__ dist2) {
    const int n = blockIdx.x;
    const int tid = threadIdx.x, wave = tid >> 6, lane = tid & 63;
    const f32x4 a = ((const f32x4*)(z_lib + (size_t)n * 1024))[tid];
    const f32x4 b = ((const f32x4*)z)[tid];
    f32x4 d = a - b;
    f32x4 s = d * d;
    float acc = s[0] + s[1] + s[2] + s[3];
    for (int off = 32; off > 0; off >>= 1) acc += __shfl_down(acc, off, 64);
    __shared__ float ws4[4];
    if (lane == 0) ws4[wave] = acc;
    __syncthreads();
    if (tid == 0) dist2[n] = ws4[0] + ws4[1] + ws4[2] + ws4[3];
}

// ---------------------------------------------------------------------------
// Kernel 2: rank-select k smallest -> idx[rank]=n, z_score; init smin bits.
// ---------------------------------------------------------------------------
__global__ __launch_bounds__(128)
void select_kernel(const float* __restrict__ dist2, const int* __restrict__ kp,
                   float* __restrict__ zscore, int* __restrict__ idx,
                   unsigned* __restrict__ sb0, unsigned* __restrict__ sb1,
                   unsigned* __restrict__ sb2) {
    __shared__ float d[NLIB];
    __shared__ float contrib[NLIB];
    const int tid = threadIdx.x;
    d[tid] = dist2[tid];
    for (int i = tid; i < 3136; i += 128) sb0[i] = INFBITS;
    for (int i = tid; i < 784;  i += 128) sb1[i] = INFBITS;
    for (int i = tid; i < 196;  i += 128) sb2[i] = INFBITS;
    __syncthreads();
    const int k = *kp;
    const float dd = d[tid];
    int rank = 0;
#pragma unroll 8
    for (int m = 0; m < NLIB; ++m) {
        const float dm = d[m];
        rank += (dm < dd || (dm == dd && m < tid)) ? 1 : 0;
    }
    if (rank < k) idx[rank] = tid;
    contrib[tid] = (rank < k) ? sqrtf(dd) : 0.f;
    __syncthreads();
    if (tid == 0) {
        float s = 0.f;
        for (int m = 0; m < NLIB; ++m) s += contrib[m];   // fixed order
        zscore[0] = s / (float)k;
    }
}

// ---------------------------------------------------------------------------
// Kernel 3: FUSED dist+min, XCD-byte-balanced. Every tile = 262KB of lib
// regardless of level: QT quads x C channels with QT = 64/32/16 for
// C = 256/512/1024. 24 uniform tiles per n; gridDim.x=24 -> tile t pins to
// XCD t%8 (fmap slice stays L2-resident) with equal bytes per XCD.
// Block: 256 thr = QT quads x G ch-groups (64 ch each); LDS-combine in fixed
// order; atomicMin(uint bits) into smin. No intermediate buffer.
// ---------------------------------------------------------------------------
template <int C, int NQ, int QT>
static __device__ __forceinline__ void dist_min_level(const float* __restrict__ lib,
                                                      const float* __restrict__ fmap,
                                                      int img, int qt,
                                                      unsigned* __restrict__ sb,
                                                      f32x4* __restrict__ part) {
    constexpr int G  = 256 / QT;       // channel groups per block
    constexpr int CW = C / G;          // channels per thread (= 64)
    const int tid = threadIdx.x;
    const int ql  = tid & (QT - 1);
    const int g   = tid / QT;
    const int q   = qt * QT + ql;
    const int qc  = q < NQ ? q : NQ - 1;     // clamp: dup same-address loads
    const f32x4* __restrict__ lp = (const f32x4*)lib + ((size_t)img * C + g * CW) * NQ + qc;
    const f32x4* __restrict__ fp = (const f32x4*)fmap + ((size_t)g * CW) * NQ + qc;
    f32x4 acc = {};
#pragma unroll 8
    for (int c = 0; c < CW; ++c) {
        f32x4 a = lp[(size_t)c * NQ];
        f32x4 f = fp[(size_t)c * NQ];
        f32x4 d = a - f;
        acc += d * d;
    }
    part[tid] = acc;
    __syncthreads();
    if (tid < QT && q < NQ) {
        f32x4 s = part[tid];
#pragma unroll
        for (int gg = 1; gg < G; ++gg) s += part[gg * QT + tid];  // fixed order
        atomicMin(sb + q * 4 + 0, __float_as_uint(s[0]));
        atomicMin(sb + q * 4 + 1, __float_as_uint(s[1]));
        atomicMin(sb + q * 4 + 2, __float_as_uint(s[2]));
        atomicMin(sb + q * 4 + 3, __float_as_uint(s[3]));
    }
}

__global__ __launch_bounds__(256)
void dist_min_kernel(const float* __restrict__ lib0, const float* __restrict__ fmap0,
                     const float* __restrict__ lib1, const float* __restrict__ fmap1,
                     const float* __restrict__ lib2, const float* __restrict__ fmap2,
                     const int* __restrict__ kp, const int* __restrict__ idx,
                     unsigned* __restrict__ sb0, unsigned* __restrict__ sb1,
                     unsigned* __restrict__ sb2) {
    __shared__ f32x4 part[256];
    const int n = blockIdx.y;
    if (n >= *kp) return;
    const int t = blockIdx.x;                 // 0..23, pins to XCD t%8
    const int img = idx[n];
    if (t < 13)      dist_min_level<256, 784, 64>(lib0, fmap0, img, t, sb0, part);       // 13 tiles
    else if (t < 20) dist_min_level<512, 196, 32>(lib1, fmap1, img, t - 13, sb1, part);  // 7 tiles
    else             dist_min_level<1024, 49, 16>(lib2, fmap2, img, t - 20, sb2, part);  // 4 tiles
}

// ---------------------------------------------------------------------------
// Kernel 4: bilinear upsample (half-pixel, edge clamp) of sqrt(smin-bits),
// summed across levels, fused with horizontal 17-tap blur (reflect).
// ---------------------------------------------------------------------------
static __device__ __forceinline__ void samp(int o, float inv_f, int sz, int& i0, int& i1,
                                            float& fr) {
    float c  = (o + 0.5f) * inv_f - 0.5f;   // inv_f power of two: exact
    float fl = floorf(c);
    fr = c - fl;
    int i = (int)fl;
    i0 = iclamp(i, 0, sz - 1);
    i1 = iclamp(i + 1, 0, sz - 1);
}

static __device__ __forceinline__ float ldsq(const unsigned* __restrict__ sb, int w, int y, int x) {
    return sqrtf(__uint_as_float(sb[y * w + x]));
}

static __device__ __forceinline__ float bilerp_sq(const unsigned* __restrict__ sb, int w,
                                                  int y0, int y1, int x0, int x1,
                                                  float fy, float fx) {
    float a = ldsq(sb, w, y0, x0), b = ldsq(sb, w, y0, x1);
    float c = ldsq(sb, w, y1, x0), d = ldsq(sb, w, y1, x1);
    float top = a + (b - a) * fx;
    float bot = c + (d - c) * fx;
    return top + (bot - top) * fy;
}

static __device__ __forceinline__ int reflect224(int i) {
    if (i < 0) i = -i;
    if (i > 223) i = 446 - i;
    return i;
}

static __device__ __forceinline__ void gauss_w(float* w) {
    float tot = 0.f;
#pragma unroll
    for (int j = 0; j < 17; ++j) {
        float t = (j - 8) * 0.25f;
        w[j] = expf(-0.5f * t * t);
        tot += w[j];
    }
    float inv = 1.f / tot;
#pragma unroll
    for (int j = 0; j < 17; ++j) w[j] *= inv;
}

__global__ __launch_bounds__(256)
void up_blurh_kernel(const unsigned* __restrict__ sb0, const unsigned* __restrict__ sb1,
                     const unsigned* __restrict__ sb2, float* __restrict__ tmp) {
    __shared__ float row[224];
    const int y = blockIdx.x, x = threadIdx.x;
    int y0, y1, x0, x1; float fy, fx;
    if (x < 224) {
        float v = 0.f;
        samp(y, 0.25f, 56, y0, y1, fy);   samp(x, 0.25f, 56, x0, x1, fx);
        v += bilerp_sq(sb0, 56, y0, y1, x0, x1, fy, fx);
        samp(y, 0.125f, 28, y0, y1, fy);  samp(x, 0.125f, 28, x0, x1, fx);
        v += bilerp_sq(sb1, 28, y0, y1, x0, x1, fy, fx);
        samp(y, 0.0625f, 14, y0, y1, fy); samp(x, 0.0625f, 14, x0, x1, fx);
        v += bilerp_sq(sb2, 14, y0, y1, x0, x1, fy, fx);
        row[x] = v;
    }
    __syncthreads();
    if (x < 224) {
        float w[17];
        gauss_w(w);
        float acc = 0.f;
#pragma unroll
        for (int j = 0; j < 17; ++j) acc += w[j] * row[reflect224(x + j - 8)];
        tmp[y * 224 + x] = acc;
    }
}

__global__ __launch_bounds__(256)
void blur_v_kernel(const float* __restrict__ in, float* __restrict__ out) {
    const int i = blockIdx.x * blockDim.x + threadIdx.x;
    if (i >= 224 * 224) return;
    const int y = i / 224, x = i % 224;
    float w[17];
    gauss_w(w);
    float acc = 0.f;
#pragma unroll
    for (int j = 0; j < 17; ++j) acc += w[j] * in[reflect224(y + j - 8) * 224 + x];
    out[i] = acc;
}

// ---------------------------------------------------------------------------
// Launch
// ---------------------------------------------------------------------------
extern "C" void kernel_launch(void* const* d_in, const int* in_sizes, int n_in,
                              void* d_out, int out_size, void* d_ws, size_t ws_size,
                              hipStream_t stream) {
    const float* z     = (const float*)d_in[0];
    const float* z_lib = (const float*)d_in[1];
    const float* fmap0 = (const float*)d_in[2];
    const float* fmap1 = (const float*)d_in[3];
    const float* fmap2 = (const float*)d_in[4];
    const float* lib0  = (const float*)d_in[5];
    const float* lib1  = (const float*)d_in[6];
    const float* lib2  = (const float*)d_in[7];
    const int*   kp    = (const int*)d_in[8];
    float* out = (float*)d_out;

    // workspace layout (16B aligned)
    constexpr size_t OFF_IDX   = 0;        // 128 i32
    constexpr size_t OFF_DIST2 = 1024;     // 128 f32
    constexpr size_t OFF_SB0   = 2048;     // 3136 u32
    constexpr size_t OFF_SB1   = 16384;    // 784 u32
    constexpr size_t OFF_SB2   = 20480;    // 196 u32
    constexpr size_t OFF_TMP   = 24576;    // 50176 f32

    char* ws = (char*)d_ws;
    int*      idx   = (int*)(ws + OFF_IDX);
    float*    dist2 = (float*)(ws + OFF_DIST2);
    unsigned* sb0   = (unsigned*)(ws + OFF_SB0);
    unsigned* sb1   = (unsigned*)(ws + OFF_SB1);
    unsigned* sb2   = (unsigned*)(ws + OFF_SB2);
    float*    tmp   = (float*)(ws + OFF_TMP);

    // 1) row distances (parallel across 128 blocks)
    row_dist_kernel<<<dim3(NLIB), dim3(256), 0, stream>>>(z, z_lib, dist2);
    // 2) rank-select + z_score + smin init
    select_kernel<<<dim3(1), dim3(128), 0, stream>>>(dist2, kp, out, idx, sb0, sb1, sb2);
    // 3) fused per-level distances + min, 24 byte-uniform tiles per n
    dist_min_kernel<<<dim3(24, NLIB), dim3(256), 0, stream>>>(
        lib0, fmap0, lib1, fmap1, lib2, fmap2, kp, idx, sb0, sb1, sb2);
    // 4) upsample + sum + blur-H
    up_blurh_kernel<<<dim3(224), dim3(256), 0, stream>>>(sb0, sb1, sb2, tmp);
    // 5) blur-V
    blur_v_kernel<<<dim3(196), dim3(256), 0, stream>>>(tmp, out + 1);
}